// Round 1
// baseline (186.811 us; speedup 1.0000x reference)
//
#include <hip/hip_runtime.h>
#include <hip/hip_bf16.h>
#include <stdint.h>

typedef __attribute__((ext_vector_type(4))) float f32x4;
typedef __attribute__((ext_vector_type(8))) __bf16 bf16x8;
typedef __attribute__((ext_vector_type(8))) unsigned short ushort8;

#define DEV static __device__ __forceinline__

// 120 MB static scratch: xn(16M) | Qs,K,Vt(48M) | attn(16M) | Wbf(8M) | S(32M)
__device__ __align__(4096) unsigned char g_scratch[125829120];

DEV unsigned short f2bf(float f) {
  union { float f; uint32_t u; } x; x.f = f;
  uint32_t u = x.u;
  uint32_t r = (u + 0x7fffu + ((u >> 16) & 1u)) >> 16;  // RNE
  return (unsigned short)r;
}
DEV float bf2f(unsigned short b) {
  union { uint32_t u; float f; } x; x.u = ((uint32_t)b) << 16;
  return x.f;
}

DEV void gload16(const void* g, void* l) {
  __builtin_amdgcn_global_load_lds((const __attribute__((address_space(1))) void*)g,
                                   (__attribute__((address_space(3))) void*)l,
                                   16, 0, 0);
}

// XOR swizzle on byte offsets within a [128 rows][128 bytes] tile.
// Involution: modifies bits 4-6 using untouched bits 7-9 (row). Spreads the
// 16-lane frag-read (stride 128B) across all 8 16B slots -> 2-way max (free).
DEV int swz(int b) { return b ^ (((b >> 7) & 7) << 4); }

// ---------------------------------------------------------------------------
// Generic bf16 GEMM: C = A(MxK) * B(NxK)^T, tiles 128x128, BK=64, 256 thr.
// OP: 0 = QKV epilogue (z: 0=Q scale+bq, 1=K +bk, 2=V +bv transposed store)
//     1 = scores (bf16, no bias)   2 = PV (bf16, no bias)
//     3 = out-proj (fp32 + bias bs0)
// ---------------------------------------------------------------------------
template<int OP>
__global__ __launch_bounds__(256, 2)
void gemm_bt(const unsigned short* __restrict__ A, const unsigned short* __restrict__ B,
             void* __restrict__ C,
             const float* __restrict__ bs0, const float* __restrict__ bs1,
             const float* __restrict__ bs2,
             int ldA, int ldB, int ldC, int K,
             long sAz, long sBz, long sCz)
{
  __shared__ unsigned short lds[16384];  // A: bytes [0,16K), B: [16K,32K)
  const int tid  = threadIdx.x;
  const int lane = tid & 63;
  const int wave = tid >> 6;
  const int z  = blockIdx.z;
  const int m0 = blockIdx.x * 128;
  const int n0 = blockIdx.y * 128;
  const unsigned short* Az = A + (size_t)z * sAz;
  const unsigned short* Bz = B + (size_t)z * sBz;
  const int wm = (wave >> 1) * 64;
  const int wn = (wave & 1) * 64;

  // fragment ds_read byte offsets (h toggles bit 6 after swizzle)
  int aOff[4], bOff[4];
#pragma unroll
  for (int m = 0; m < 4; ++m) {
    int ar = wm + m * 16 + (lane & 15);
    aOff[m] = (ar * 128 + ((lane >> 4) * 16)) ^ ((ar & 7) << 4);
    int br = wn + m * 16 + (lane & 15);
    bOff[m] = ((br * 128 + ((lane >> 4) * 16)) ^ ((br & 7) << 4)) + 16384;
  }

  f32x4 acc[4][4] = {};

  const unsigned short* a_t = Az + (size_t)m0 * ldA;
  const unsigned short* b_t = Bz + (size_t)n0 * ldB;

  for (int kt = 0; kt < K; kt += 64) {
#pragma unroll
    for (int i = 0; i < 4; ++i) {
      int o = i * 4096 + tid * 16;      // linear LDS byte offset (wave-uniform base + lane*16)
      int p = swz(o);                   // logical tile position stored here
      int row = p >> 7;
      int ce  = (p & 127) >> 1;         // element col within tile
      gload16(a_t + (size_t)row * ldA + (kt + ce), (char*)lds + o);
      gload16(b_t + (size_t)row * ldB + (kt + ce), (char*)lds + 16384 + o);
    }
    __syncthreads();
#pragma unroll
    for (int h = 0; h < 2; ++h) {
      bf16x8 av[4], bv4[4];
#pragma unroll
      for (int m = 0; m < 4; ++m)
        av[m] = *(const bf16x8*)((const char*)lds + (aOff[m] ^ (h << 6)));
#pragma unroll
      for (int n = 0; n < 4; ++n)
        bv4[n] = *(const bf16x8*)((const char*)lds + (bOff[n] ^ (h << 6)));
#pragma unroll
      for (int m = 0; m < 4; ++m)
#pragma unroll
        for (int n = 0; n < 4; ++n)
          acc[m][n] = __builtin_amdgcn_mfma_f32_16x16x32_bf16(av[m], bv4[n], acc[m][n], 0, 0, 0);
    }
    __syncthreads();
  }

  // epilogue: D frag layout col=lane&15, row=(lane>>4)*4+i  [m89-verified]
  const int r0 = (lane >> 4) * 4;
  const int cL = lane & 15;

  if (OP == 0) {
    const float* bias = (z == 0) ? bs0 : ((z == 1) ? bs1 : bs2);
    if (z < 2) {
      const float scale = (z == 0) ? 0.03125f : 1.0f;  // fold 1/sqrt(D) into Q
      unsigned short* Cp = (unsigned short*)C + (size_t)z * sCz;
#pragma unroll
      for (int n = 0; n < 4; ++n) {
        int colg = n0 + wn + n * 16 + cL;
        float bb = bias[colg];
#pragma unroll
        for (int m = 0; m < 4; ++m) {
          int rowg = m0 + wm + m * 16 + r0;
#pragma unroll
          for (int i = 0; i < 4; ++i)
            Cp[(size_t)(rowg + i) * ldC + colg] = f2bf((acc[m][n][i] + bb) * scale);
        }
      }
    } else {
      // V stored transposed per batch: Vt[b][e][s], 4 consecutive s -> 8B store
      unsigned short* Vt = (unsigned short*)C + (size_t)2 * sCz;
#pragma unroll
      for (int n = 0; n < 4; ++n) {
        int colg = n0 + wn + n * 16 + cL;          // e
        float bb = bias[colg];
#pragma unroll
        for (int m = 0; m < 4; ++m) {
          int rowg = m0 + wm + m * 16 + r0;        // global s (0..8191)
          int bat = rowg >> 11, s = rowg & 2047;
          ushort4 pk;
          pk.x = f2bf(acc[m][n][0] + bb);
          pk.y = f2bf(acc[m][n][1] + bb);
          pk.z = f2bf(acc[m][n][2] + bb);
          pk.w = f2bf(acc[m][n][3] + bb);
          *(ushort4*)(Vt + (size_t)bat * 2097152 + (size_t)colg * 2048 + s) = pk;
        }
      }
    }
  } else if (OP == 3) {
    float* Cp = (float*)C;
#pragma unroll
    for (int n = 0; n < 4; ++n) {
      int colg = n0 + wn + n * 16 + cL;
      float bb = bs0[colg];
#pragma unroll
      for (int m = 0; m < 4; ++m) {
        int rowg = m0 + wm + m * 16 + r0;
#pragma unroll
        for (int i = 0; i < 4; ++i)
          Cp[(size_t)(rowg + i) * ldC + colg] = acc[m][n][i] + bb;
      }
    }
  } else {
    unsigned short* Cp = (unsigned short*)C + (size_t)z * sCz;
#pragma unroll
    for (int n = 0; n < 4; ++n) {
      int colg = n0 + wn + n * 16 + cL;
#pragma unroll
      for (int m = 0; m < 4; ++m) {
        int rowg = m0 + wm + m * 16 + r0;
#pragma unroll
        for (int i = 0; i < 4; ++i)
          Cp[(size_t)(rowg + i) * ldC + colg] = f2bf(acc[m][n][i]);
      }
    }
  }
}

// ---------------------------------------------------------------------------
__global__ __launch_bounds__(256)
void cvt_w(const float* __restrict__ w0, const float* __restrict__ w1,
           const float* __restrict__ w2, const float* __restrict__ w3,
           unsigned short* __restrict__ dst)
{
  const float* src = (blockIdx.y == 0) ? w0 : (blockIdx.y == 1) ? w1
                   : (blockIdx.y == 2) ? w2 : w3;
  const int idx = (blockIdx.x * 256 + threadIdx.x) * 8;
  const float4 a = *(const float4*)(src + idx);
  const float4 b = *(const float4*)(src + idx + 4);
  unsigned short* d = dst + (size_t)blockIdx.y * 1048576 + idx;
  ushort4 r0, r1;
  r0.x = f2bf(a.x); r0.y = f2bf(a.y); r0.z = f2bf(a.z); r0.w = f2bf(a.w);
  r1.x = f2bf(b.x); r1.y = f2bf(b.y); r1.z = f2bf(b.z); r1.w = f2bf(b.w);
  *(ushort4*)(d) = r0;
  *(ushort4*)(d + 4) = r1;
}

__global__ __launch_bounds__(256)
void ln_kernel(const float* __restrict__ x, const float* __restrict__ gamma,
               const float* __restrict__ beta, unsigned short* __restrict__ xn)
{
  const int row = blockIdx.x;
  const int tid = threadIdx.x;
  const float4 xv = ((const float4*)(x + (size_t)row * 1024))[tid];
  float s = xv.x + xv.y + xv.z + xv.w;
#pragma unroll
  for (int d = 1; d < 64; d <<= 1) s += __shfl_xor(s, d);
  __shared__ float red1[4], red2[4];
  const int lane = tid & 63, wv = tid >> 6;
  if (lane == 0) red1[wv] = s;
  __syncthreads();
  const float mu = (red1[0] + red1[1] + red1[2] + red1[3]) * (1.0f / 1024.0f);
  float4 dv;
  dv.x = xv.x - mu; dv.y = xv.y - mu; dv.z = xv.z - mu; dv.w = xv.w - mu;
  float vs = dv.x * dv.x + dv.y * dv.y + dv.z * dv.z + dv.w * dv.w;
#pragma unroll
  for (int d = 1; d < 64; d <<= 1) vs += __shfl_xor(vs, d);
  if (lane == 0) red2[wv] = vs;
  __syncthreads();
  const float var = (red2[0] + red2[1] + red2[2] + red2[3]) * (1.0f / 1024.0f);
  const float rs = rsqrtf(var + 1e-5f);
  const float4 g = ((const float4*)gamma)[tid];
  const float4 b = ((const float4*)beta)[tid];
  ushort4 o;
  o.x = f2bf(dv.x * rs * g.x + b.x);
  o.y = f2bf(dv.y * rs * g.y + b.y);
  o.z = f2bf(dv.z * rs * g.z + b.z);
  o.w = f2bf(dv.w * rs * g.w + b.w);
  ((ushort4*)(xn + (size_t)row * 1024))[tid] = o;
}

__global__ __launch_bounds__(256)
void softmax_kernel(unsigned short* __restrict__ S)
{
  const size_t row = blockIdx.x;
  unsigned short* p = S + row * 2048;
  const int tid = threadIdx.x;
  ushort8 v = ((const ushort8*)p)[tid];
  float f[8];
#pragma unroll
  for (int j = 0; j < 8; ++j) f[j] = bf2f(v[j]);
  float mx = f[0];
#pragma unroll
  for (int j = 1; j < 8; ++j) mx = fmaxf(mx, f[j]);
#pragma unroll
  for (int d = 1; d < 64; d <<= 1) mx = fmaxf(mx, __shfl_xor(mx, d));
  __shared__ float rmax[4], rsum[4];
  const int lane = tid & 63, wv = tid >> 6;
  if (lane == 0) rmax[wv] = mx;
  __syncthreads();
  const float M = fmaxf(fmaxf(rmax[0], rmax[1]), fmaxf(rmax[2], rmax[3]));
  float e[8], sum = 0.f;
#pragma unroll
  for (int j = 0; j < 8; ++j) { e[j] = __expf(f[j] - M); sum += e[j]; }
#pragma unroll
  for (int d = 1; d < 64; d <<= 1) sum += __shfl_xor(sum, d);
  if (lane == 0) rsum[wv] = sum;
  __syncthreads();
  const float inv = 1.0f / (rsum[0] + rsum[1] + rsum[2] + rsum[3]);
#pragma unroll
  for (int j = 0; j < 8; ++j) v[j] = f2bf(e[j] * inv);
  ((ushort8*)p)[tid] = v;
}

// ---------------------------------------------------------------------------
extern "C" void kernel_launch(void* const* d_in, const int* in_sizes, int n_in,
                              void* d_out, int out_size, void* d_ws, size_t ws_size,
                              hipStream_t stream) {
  const float* x     = (const float*)d_in[0];
  const float* gamma = (const float*)d_in[1];
  const float* beta  = (const float*)d_in[2];
  const float* Wq    = (const float*)d_in[3];
  const float* bq    = (const float*)d_in[4];
  const float* Wk    = (const float*)d_in[5];
  const float* bk    = (const float*)d_in[6];
  const float* Wv    = (const float*)d_in[7];
  const float* bv    = (const float*)d_in[8];
  const float* Wo    = (const float*)d_in[9];
  const float* bo    = (const float*)d_in[10];

  char* ws;
  if (ws_size >= (size_t)125829120) {
    ws = (char*)d_ws;
  } else {
    void* sp = nullptr;
    hipGetSymbolAddress(&sp, HIP_SYMBOL(g_scratch));
    ws = (char*)sp;
  }

  unsigned short* xn  = (unsigned short*)(ws);              // 8192x1024 bf16
  unsigned short* qkv = (unsigned short*)(ws + 16777216);   // Qs | K | Vt (each 8M elems)
  unsigned short* att = (unsigned short*)(ws + 67108864);   // 8192x1024 bf16
  unsigned short* wbf = (unsigned short*)(ws + 83886080);   // Wq|Wk|Wv|Wo bf16
  unsigned short* S   = (unsigned short*)(ws + 92274688);   // 4 x 2048 x 2048 bf16

  cvt_w<<<dim3(512, 4, 1), 256, 0, stream>>>(Wq, Wk, Wv, Wo, wbf);
  ln_kernel<<<8192, 256, 0, stream>>>(x, gamma, beta, xn);
  // Q/K/V projections: xn @ W^T + b   (Q scaled by 1/32, V stored transposed)
  gemm_bt<0><<<dim3(64, 8, 3), 256, 0, stream>>>(
      xn, wbf, qkv, bq, bk, bv,
      1024, 1024, 1024, 1024, 0L, 1048576L, 8388608L);
  // scores = Qs @ K^T  (per batch)
  gemm_bt<1><<<dim3(16, 16, 4), 256, 0, stream>>>(
      qkv, qkv + 8388608, S, nullptr, nullptr, nullptr,
      1024, 1024, 2048, 1024, 2097152L, 2097152L, 4194304L);
  softmax_kernel<<<8192, 256, 0, stream>>>(S);
  // attn_out = P @ Vt^T (per batch)
  gemm_bt<2><<<dim3(16, 8, 4), 256, 0, stream>>>(
      S, qkv + 16777216, att, nullptr, nullptr, nullptr,
      2048, 2048, 1024, 2048, 4194304L, 2097152L, 2097152L);
  // out = attn @ Wo^T + bo  (fp32)
  gemm_bt<3><<<dim3(64, 8, 1), 256, 0, stream>>>(
      att, wbf + 3145728, d_out, bo, nullptr, nullptr,
      1024, 1024, 1024, 1024, 0L, 0L, 0L);
}